// Round 1
// baseline (664.207 us; speedup 1.0000x reference)
//
#include <hip/hip_runtime.h>

// Problem constants
#define TT   26
#define RR   100000
#define DD   128
#define NN   10
#define BB   16384
#define NUMF 13
#define KP0  3392   // T*D+NUM = 3341 padded to 53*64

typedef __bf16 bf16x8 __attribute__((ext_vector_type(8)));
typedef float  f32x4  __attribute__((ext_vector_type(4)));

__device__ __forceinline__ unsigned short f2bf(float f) {
    unsigned int u = __float_as_uint(f);
    u += 0x7FFFu + ((u >> 16) & 1u);          // round-to-nearest-even
    return (unsigned short)(u >> 16);
}

__device__ __forceinline__ void gload_lds16(const void* g, void* l) {
    __builtin_amdgcn_global_load_lds(
        (const __attribute__((address_space(1))) void*)g,
        (__attribute__((address_space(3))) void*)l, 16, 0, 0);
}

// ---------------- weight transpose + f32->bf16 (W[K][N] -> Wt[N][KPad]) ----------------
__global__ __launch_bounds__(256) void transpose_cvt(
    const float* __restrict__ in, unsigned short* __restrict__ out,
    int Kin, int KPad, int N)
{
    __shared__ float tile[64][65];
    int k0 = blockIdx.x * 64;
    int n0 = blockIdx.y * 64;
    int c  = threadIdx.x & 63;
    int rr = threadIdx.x >> 6;          // 0..3
    #pragma unroll
    for (int r = rr; r < 64; r += 4) {
        int k = k0 + r, n = n0 + c;
        float v = 0.f;
        if (k < Kin && n < N) v = in[(size_t)k * N + n];
        tile[r][c] = v;
    }
    __syncthreads();
    #pragma unroll
    for (int r = rr; r < 64; r += 4) {
        int n = n0 + r, kp = k0 + c;
        if (n < N && kp < KPad)
            out[(size_t)n * KPad + kp] = f2bf(tile[c][r]);
    }
}

// ---------------- embedding bag: one wave per (b,t); sum 10 rows of 128 floats ----------
__global__ __launch_bounds__(256) void embed_bag(
    const float* __restrict__ tables, const int* __restrict__ cat,
    unsigned short* __restrict__ x)
{
    int wid  = blockIdx.x * 4 + (threadIdx.x >> 6);   // bag id = b*T + t
    int lane = threadIdx.x & 63;
    int b = wid / TT;
    int t = wid - b * TT;
    const int* ip = cat + (size_t)wid * NN;           // wave-uniform -> s_load
    const float* tbase = tables + (size_t)t * RR * DD;
    float ax = 0.f, ay = 0.f;
    #pragma unroll
    for (int n = 0; n < NN; n++) {
        int r = ip[n];
        float2 v = *(const float2*)(tbase + (size_t)r * DD + lane * 2);
        ax += v.x; ay += v.y;
    }
    unsigned int packed = (unsigned int)f2bf(ax) | ((unsigned int)f2bf(ay) << 16);
    *(unsigned int*)(x + (size_t)b * KP0 + t * DD + lane * 2) = packed;
}

// ---------------- numerical features + zero pad into x cols [3328,3392) ----------------
__global__ __launch_bounds__(256) void num_fill(
    const float* __restrict__ numerical, unsigned short* __restrict__ x)
{
    int b    = blockIdx.x * 4 + (threadIdx.x >> 6);
    int lane = threadIdx.x & 63;
    unsigned short v = 0;
    if (lane < NUMF) v = f2bf(numerical[b * NUMF + lane]);
    x[(size_t)b * KP0 + TT * DD + lane] = v;
}

// ---------------- bf16 MFMA GEMM: C[M][N] = relu(A[M][K] @ Bt[N][K]^T + bias) ----------
// 128x128 tile, BK=64, 256 threads (4 waves, 2x2), m97-style global_load_lds staging.
__device__ __forceinline__ void stage_tile(
    const unsigned short* __restrict__ src,   // base already offset by row0*K
    unsigned short* lds, int K, int k0, int tid)
{
    #pragma unroll
    for (int j = 0; j < 4; j++) {
        int ch = j * 256 + tid;                       // chunk 0..1023, 16B each
        const unsigned short* g = src + (size_t)(ch >> 3) * K + k0 + (ch & 7) * 8;
        gload_lds16(g, lds + (size_t)(j * 256 + (tid & 192)) * 8);
    }
}

__global__ __launch_bounds__(256) void gemm_bias_relu(
    const unsigned short* __restrict__ A,    // [M][K] bf16
    const unsigned short* __restrict__ Bt,   // [N][K] bf16 (pre-transposed weight)
    const float* __restrict__ bias,          // [N]
    unsigned short* __restrict__ C,          // [M][N] bf16
    int M, int N, int K, int do_relu)
{
    __shared__ __align__(16) unsigned short As[128 * 64];
    __shared__ __align__(16) unsigned short Bs[128 * 64];

    const int tid  = threadIdx.x;
    const int lane = tid & 63;
    const int w    = tid >> 6;
    const int wm   = w >> 1, wn = w & 1;
    const int m0   = blockIdx.y * 128, n0 = blockIdx.x * 128;

    f32x4 acc[4][4];
    #pragma unroll
    for (int i = 0; i < 4; i++)
        #pragma unroll
        for (int j = 0; j < 4; j++) {
            f32x4 z = {0.f, 0.f, 0.f, 0.f};
            acc[i][j] = z;
        }

    const unsigned short* Abase = A  + (size_t)m0 * K;
    const unsigned short* Bbase = Bt + (size_t)n0 * K;

    for (int k0 = 0; k0 < K; k0 += 64) {
        stage_tile(Abase, As, K, k0, tid);
        stage_tile(Bbase, Bs, K, k0, tid);
        __syncthreads();
        #pragma unroll
        for (int kk = 0; kk < 2; kk++) {
            bf16x8 af[4], bfv[4];
            #pragma unroll
            for (int mi = 0; mi < 4; mi++) {
                int off = (wm * 64 + mi * 16 + (lane & 15)) * 64 + kk * 32 + (lane >> 4) * 8;
                af[mi] = *(const bf16x8*)(As + off);
            }
            #pragma unroll
            for (int ni = 0; ni < 4; ni++) {
                int off = (wn * 64 + ni * 16 + (lane & 15)) * 64 + kk * 32 + (lane >> 4) * 8;
                bfv[ni] = *(const bf16x8*)(Bs + off);
            }
            #pragma unroll
            for (int mi = 0; mi < 4; mi++)
                #pragma unroll
                for (int ni = 0; ni < 4; ni++)
                    acc[mi][ni] = __builtin_amdgcn_mfma_f32_16x16x32_bf16(
                        af[mi], bfv[ni], acc[mi][ni], 0, 0, 0);
        }
        __syncthreads();
    }

    // epilogue: bias + relu + bf16 store.  C/D map: col=lane&15, row=4*(lane>>4)+j
    #pragma unroll
    for (int mi = 0; mi < 4; mi++) {
        int row_base = m0 + wm * 64 + mi * 16 + (lane >> 4) * 4;
        #pragma unroll
        for (int ni = 0; ni < 4; ni++) {
            int col = n0 + wn * 64 + ni * 16 + (lane & 15);
            float bv = bias[col];
            #pragma unroll
            for (int j = 0; j < 4; j++) {
                float v = acc[mi][ni][j] + bv;
                if (do_relu) v = v > 0.f ? v : 0.f;
                C[(size_t)(row_base + j) * N + col] = f2bf(v);
            }
        }
    }
}

// ---------------- final layer: out[b] = h3[b][:256] . W3 + b3 (one wave per row) -------
__global__ __launch_bounds__(256) void final_dot(
    const unsigned short* __restrict__ h3, const float* __restrict__ W3,
    const float* __restrict__ b3, float* __restrict__ out)
{
    int b    = blockIdx.x * 4 + (threadIdx.x >> 6);
    int lane = threadIdx.x & 63;
    uint2 u = *(const uint2*)(h3 + (size_t)b * 256 + lane * 4);
    float f0 = __uint_as_float((u.x & 0xffffu) << 16);
    float f1 = __uint_as_float(u.x & 0xffff0000u);
    float f2 = __uint_as_float((u.y & 0xffffu) << 16);
    float f3 = __uint_as_float(u.y & 0xffff0000u);
    float4 wv = *(const float4*)(W3 + lane * 4);
    float s = f0 * wv.x + f1 * wv.y + f2 * wv.z + f3 * wv.w;
    #pragma unroll
    for (int off = 32; off > 0; off >>= 1) s += __shfl_down(s, off, 64);
    if (lane == 0) out[b] = s + b3[0];
}

extern "C" void kernel_launch(void* const* d_in, const int* in_sizes, int n_in,
                              void* d_out, int out_size, void* d_ws, size_t ws_size,
                              hipStream_t stream)
{
    const float* numerical = (const float*)d_in[0];
    const int*   cat       = (const int*)d_in[1];
    const float* tables    = (const float*)d_in[2];
    const float* W0 = (const float*)d_in[3];
    const float* b0 = (const float*)d_in[4];
    const float* W1 = (const float*)d_in[5];
    const float* b1 = (const float*)d_in[6];
    const float* W2 = (const float*)d_in[7];
    const float* b2 = (const float*)d_in[8];
    const float* W3 = (const float*)d_in[9];
    const float* b3 = (const float*)d_in[10];
    float* out = (float*)d_out;

    // workspace layout (bf16 elements); h2/h3 alias x (dead after L0)
    unsigned short* x   = (unsigned short*)d_ws;            // [16384][3392]
    unsigned short* w0t = x   + (size_t)BB * KP0;           // [1024][3392]
    unsigned short* w1t = w0t + (size_t)1024 * KP0;         // [512][1024]
    unsigned short* w2t = w1t + (size_t)512 * 1024;         // [256][512]
    unsigned short* h1  = w2t + (size_t)256 * 512;          // [16384][1024]
    unsigned short* h2  = x;                                // [16384][512]
    unsigned short* h3  = x   + (size_t)BB * 512;           // [16384][256]

    transpose_cvt<<<dim3(53, 16), 256, 0, stream>>>(W0, w0t, TT * DD + NUMF, KP0, 1024);
    transpose_cvt<<<dim3(16, 8),  256, 0, stream>>>(W1, w1t, 1024, 1024, 512);
    transpose_cvt<<<dim3(8, 4),   256, 0, stream>>>(W2, w2t, 512, 512, 256);

    embed_bag<<<dim3(BB * TT / 4), 256, 0, stream>>>(tables, cat, x);
    num_fill <<<dim3(BB / 4),      256, 0, stream>>>(numerical, x);

    gemm_bias_relu<<<dim3(8, 128), 256, 0, stream>>>(x,  w0t, b0, h1, BB, 1024, KP0, 1);
    gemm_bias_relu<<<dim3(4, 128), 256, 0, stream>>>(h1, w1t, b1, h2, BB, 512, 1024, 1);
    gemm_bias_relu<<<dim3(2, 128), 256, 0, stream>>>(h2, w2t, b2, h3, BB, 256, 512, 1);

    final_dot<<<dim3(BB / 4), 256, 0, stream>>>(h3, W3, b3, out);
}

// Round 2
// 589.195 us; speedup vs baseline: 1.1273x; 1.1273x over previous
//
#include <hip/hip_runtime.h>

// Problem constants
#define TT   26
#define RR   100000
#define DD   128
#define NN   10
#define BB   16384
#define NUMF 13
#define KP0  3392   // T*D+NUM = 3341 padded to 53*64

typedef __bf16 bf16x8 __attribute__((ext_vector_type(8)));
typedef float  f32x4  __attribute__((ext_vector_type(4)));

__device__ __forceinline__ unsigned short f2bf(float f) {
    unsigned int u = __float_as_uint(f);
    u += 0x7FFFu + ((u >> 16) & 1u);          // round-to-nearest-even
    return (unsigned short)(u >> 16);
}

__device__ __forceinline__ void gload_lds16(const void* g, void* l) {
    __builtin_amdgcn_global_load_lds(
        (const __attribute__((address_space(1))) void*)g,
        (__attribute__((address_space(3))) void*)l, 16, 0, 0);
}

// ---------------- weight transpose + f32->bf16 (W[K][N] -> Wt[N][KPad]) ----------------
__global__ __launch_bounds__(256) void transpose_cvt(
    const float* __restrict__ in, unsigned short* __restrict__ out,
    int Kin, int KPad, int N)
{
    __shared__ float tile[64][65];
    int k0 = blockIdx.x * 64;
    int n0 = blockIdx.y * 64;
    int c  = threadIdx.x & 63;
    int rr = threadIdx.x >> 6;          // 0..3
    #pragma unroll
    for (int r = rr; r < 64; r += 4) {
        int k = k0 + r, n = n0 + c;
        float v = 0.f;
        if (k < Kin && n < N) v = in[(size_t)k * N + n];
        tile[r][c] = v;
    }
    __syncthreads();
    #pragma unroll
    for (int r = rr; r < 64; r += 4) {
        int n = n0 + r, kp = k0 + c;
        if (n < N && kp < KPad)
            out[(size_t)n * KPad + kp] = f2bf(tile[c][r]);
    }
}

// ---------------- embedding bag: one wave per (t,b), TABLE-MAJOR for LLC locality -------
// Sweeping tables one at a time keeps the active table (51.2 MB) resident in the
// 256 MB Infinity Cache so repeat-row gathers (touch factor 1.64) hit LLC not HBM.
__global__ __launch_bounds__(256) void embed_bag(
    const float* __restrict__ tables, const int* __restrict__ cat,
    unsigned short* __restrict__ x)
{
    int wid  = blockIdx.x * 4 + (threadIdx.x >> 6);   // t-major bag id = t*B + b
    int lane = threadIdx.x & 63;
    int t = wid >> 14;            // wid / BB
    int b = wid & (BB - 1);       // wid % BB
    const int* ip = cat + ((size_t)b * TT + t) * NN;  // wave-uniform -> s_load
    const float* tbase = tables + (size_t)t * RR * DD;
    float ax = 0.f, ay = 0.f;
    #pragma unroll
    for (int n = 0; n < NN; n++) {
        int r = ip[n];
        float2 v = *(const float2*)(tbase + (size_t)r * DD + lane * 2);
        ax += v.x; ay += v.y;
    }
    unsigned int packed = (unsigned int)f2bf(ax) | ((unsigned int)f2bf(ay) << 16);
    *(unsigned int*)(x + (size_t)b * KP0 + t * DD + lane * 2) = packed;
}

// ---------------- numerical features + zero pad into x cols [3328,3392) ----------------
__global__ __launch_bounds__(256) void num_fill(
    const float* __restrict__ numerical, unsigned short* __restrict__ x)
{
    int b    = blockIdx.x * 4 + (threadIdx.x >> 6);
    int lane = threadIdx.x & 63;
    unsigned short v = 0;
    if (lane < NUMF) v = f2bf(numerical[b * NUMF + lane]);
    x[(size_t)b * KP0 + TT * DD + lane] = v;
}

// ---------------- bf16 MFMA GEMM: C[M][N] = relu(A[M][K] @ Bt[N][K]^T + bias) ----------
// 128x128 tile, BK=64, 256 threads (4 waves, 2x2), m97-style global_load_lds staging.
// Block index XCD-swizzled (bijective, grid%8==0) so one XCD's L2 reuses one A-panel.
__device__ __forceinline__ void stage_tile(
    const unsigned short* __restrict__ src,   // base already offset by row0*K
    unsigned short* lds, int K, int k0, int tid)
{
    #pragma unroll
    for (int j = 0; j < 4; j++) {
        int ch = j * 256 + tid;                       // chunk 0..1023, 16B each
        const unsigned short* g = src + (size_t)(ch >> 3) * K + k0 + (ch & 7) * 8;
        gload_lds16(g, lds + (size_t)(j * 256 + (tid & 192)) * 8);
    }
}

__global__ __launch_bounds__(256) void gemm_bias_relu(
    const unsigned short* __restrict__ A,    // [M][K] bf16
    const unsigned short* __restrict__ Bt,   // [N][K] bf16 (pre-transposed weight)
    const float* __restrict__ bias,          // [N]
    unsigned short* __restrict__ C,          // [M][N] bf16
    int M, int N, int K, int do_relu)
{
    __shared__ __align__(16) unsigned short As[128 * 64];
    __shared__ __align__(16) unsigned short Bs[128 * 64];

    const int tid  = threadIdx.x;
    const int lane = tid & 63;
    const int w    = tid >> 6;
    const int wm   = w >> 1, wn = w & 1;

    // XCD-aware bijective swizzle of the linear block id (grid.x*grid.y % 8 == 0)
    int nwg  = gridDim.x * gridDim.y;
    int orig = blockIdx.y * gridDim.x + blockIdx.x;
    int cpx  = nwg >> 3;
    int swz  = (orig & 7) * cpx + (orig >> 3);
    int bx   = swz % gridDim.x;
    int by   = swz / gridDim.x;
    const int m0 = by * 128, n0 = bx * 128;

    f32x4 acc[4][4];
    #pragma unroll
    for (int i = 0; i < 4; i++)
        #pragma unroll
        for (int j = 0; j < 4; j++) {
            f32x4 z = {0.f, 0.f, 0.f, 0.f};
            acc[i][j] = z;
        }

    const unsigned short* Abase = A  + (size_t)m0 * K;
    const unsigned short* Bbase = Bt + (size_t)n0 * K;

    for (int k0 = 0; k0 < K; k0 += 64) {
        stage_tile(Abase, As, K, k0, tid);
        stage_tile(Bbase, Bs, K, k0, tid);
        __syncthreads();
        #pragma unroll
        for (int kk = 0; kk < 2; kk++) {
            bf16x8 af[4], bfv[4];
            #pragma unroll
            for (int mi = 0; mi < 4; mi++) {
                int off = (wm * 64 + mi * 16 + (lane & 15)) * 64 + kk * 32 + (lane >> 4) * 8;
                af[mi] = *(const bf16x8*)(As + off);
            }
            #pragma unroll
            for (int ni = 0; ni < 4; ni++) {
                int off = (wn * 64 + ni * 16 + (lane & 15)) * 64 + kk * 32 + (lane >> 4) * 8;
                bfv[ni] = *(const bf16x8*)(Bs + off);
            }
            #pragma unroll
            for (int mi = 0; mi < 4; mi++)
                #pragma unroll
                for (int ni = 0; ni < 4; ni++)
                    acc[mi][ni] = __builtin_amdgcn_mfma_f32_16x16x32_bf16(
                        af[mi], bfv[ni], acc[mi][ni], 0, 0, 0);
        }
        __syncthreads();
    }

    // epilogue: bias + relu + bf16 store.  C/D map: col=lane&15, row=4*(lane>>4)+j
    #pragma unroll
    for (int mi = 0; mi < 4; mi++) {
        int row_base = m0 + wm * 64 + mi * 16 + (lane >> 4) * 4;
        #pragma unroll
        for (int ni = 0; ni < 4; ni++) {
            int col = n0 + wn * 64 + ni * 16 + (lane & 15);
            float bv = bias[col];
            #pragma unroll
            for (int j = 0; j < 4; j++) {
                float v = acc[mi][ni][j] + bv;
                if (do_relu) v = v > 0.f ? v : 0.f;
                C[(size_t)(row_base + j) * N + col] = f2bf(v);
            }
        }
    }
}

// ---------------- final layer: out[b] = h3[b][:256] . W3 + b3 (one wave per row) -------
__global__ __launch_bounds__(256) void final_dot(
    const unsigned short* __restrict__ h3, const float* __restrict__ W3,
    const float* __restrict__ b3, float* __restrict__ out)
{
    int b    = blockIdx.x * 4 + (threadIdx.x >> 6);
    int lane = threadIdx.x & 63;
    uint2 u = *(const uint2*)(h3 + (size_t)b * 256 + lane * 4);
    float f0 = __uint_as_float((u.x & 0xffffu) << 16);
    float f1 = __uint_as_float(u.x & 0xffff0000u);
    float f2 = __uint_as_float((u.y & 0xffffu) << 16);
    float f3 = __uint_as_float(u.y & 0xffff0000u);
    float4 wv = *(const float4*)(W3 + lane * 4);
    float s = f0 * wv.x + f1 * wv.y + f2 * wv.z + f3 * wv.w;
    #pragma unroll
    for (int off = 32; off > 0; off >>= 1) s += __shfl_down(s, off, 64);
    if (lane == 0) out[b] = s + b3[0];
}

extern "C" void kernel_launch(void* const* d_in, const int* in_sizes, int n_in,
                              void* d_out, int out_size, void* d_ws, size_t ws_size,
                              hipStream_t stream)
{
    const float* numerical = (const float*)d_in[0];
    const int*   cat       = (const int*)d_in[1];
    const float* tables    = (const float*)d_in[2];
    const float* W0 = (const float*)d_in[3];
    const float* b0 = (const float*)d_in[4];
    const float* W1 = (const float*)d_in[5];
    const float* b1 = (const float*)d_in[6];
    const float* W2 = (const float*)d_in[7];
    const float* b2 = (const float*)d_in[8];
    const float* W3 = (const float*)d_in[9];
    const float* b3 = (const float*)d_in[10];
    float* out = (float*)d_out;

    // workspace layout (bf16 elements); h2/h3 alias x (dead after L0)
    unsigned short* x   = (unsigned short*)d_ws;            // [16384][3392]
    unsigned short* w0t = x   + (size_t)BB * KP0;           // [1024][3392]
    unsigned short* w1t = w0t + (size_t)1024 * KP0;         // [512][1024]
    unsigned short* w2t = w1t + (size_t)512 * 1024;         // [256][512]
    unsigned short* h1  = w2t + (size_t)256 * 512;          // [16384][1024]
    unsigned short* h2  = x;                                // [16384][512]
    unsigned short* h3  = x   + (size_t)BB * 512;           // [16384][256]

    transpose_cvt<<<dim3(53, 16), 256, 0, stream>>>(W0, w0t, TT * DD + NUMF, KP0, 1024);
    transpose_cvt<<<dim3(16, 8),  256, 0, stream>>>(W1, w1t, 1024, 1024, 512);
    transpose_cvt<<<dim3(8, 4),   256, 0, stream>>>(W2, w2t, 512, 512, 256);

    embed_bag<<<dim3(BB * TT / 4), 256, 0, stream>>>(tables, cat, x);
    num_fill <<<dim3(BB / 4),      256, 0, stream>>>(numerical, x);

    gemm_bias_relu<<<dim3(8, 128), 256, 0, stream>>>(x,  w0t, b0, h1, BB, 1024, KP0, 1);
    gemm_bias_relu<<<dim3(4, 128), 256, 0, stream>>>(h1, w1t, b1, h2, BB, 512, 1024, 1);
    gemm_bias_relu<<<dim3(2, 128), 256, 0, stream>>>(h2, w2t, b2, h3, BB, 256, 512, 1);

    final_dot<<<dim3(BB / 4), 256, 0, stream>>>(h3, W3, b3, out);
}

// Round 3
// 581.661 us; speedup vs baseline: 1.1419x; 1.0130x over previous
//
#include <hip/hip_runtime.h>

// Problem constants
#define TT   26
#define RR   100000
#define DD   128
#define NN   10
#define BB   16384
#define NUMF 13
#define KP0  3392   // T*D+NUM = 3341 padded to 53*64

typedef __bf16 bf16x8 __attribute__((ext_vector_type(8)));
typedef float  f32x4  __attribute__((ext_vector_type(4)));
typedef unsigned int u32x2 __attribute__((ext_vector_type(2)));

__device__ __forceinline__ unsigned short f2bf(float f) {
    unsigned int u = __float_as_uint(f);
    u += 0x7FFFu + ((u >> 16) & 1u);          // round-to-nearest-even
    return (unsigned short)(u >> 16);
}

__device__ __forceinline__ void gload_lds16(const void* g, void* l) {
    __builtin_amdgcn_global_load_lds(
        (const __attribute__((address_space(1))) void*)g,
        (__attribute__((address_space(3))) void*)l, 16, 0, 0);
}

// ---------------- weight transpose + f32->bf16 (W[K][N] -> Wt[N][KPad]) ----------------
__global__ __launch_bounds__(256) void transpose_cvt(
    const float* __restrict__ in, unsigned short* __restrict__ out,
    int Kin, int KPad, int N)
{
    __shared__ float tile[64][65];
    int k0 = blockIdx.x * 64;
    int n0 = blockIdx.y * 64;
    int c  = threadIdx.x & 63;
    int rr = threadIdx.x >> 6;          // 0..3
    #pragma unroll
    for (int r = rr; r < 64; r += 4) {
        int k = k0 + r, n = n0 + c;
        float v = 0.f;
        if (k < Kin && n < N) v = in[(size_t)k * N + n];
        tile[r][c] = v;
    }
    __syncthreads();
    #pragma unroll
    for (int r = rr; r < 64; r += 4) {
        int n = n0 + r, kp = k0 + c;
        if (n < N && kp < KPad)
            out[(size_t)n * KPad + kp] = f2bf(tile[c][r]);
    }
}

// ---------------- embedding bag: one wave per (t,b), TABLE-MAJOR for LLC locality -------
// Two rows gathered per instruction: lanes 0-31 take the even row, lanes 32-63 the odd
// row, 16B/lane -> 5x global_load_dwordx4 (1KiB/instr). One shfl_xor(32) combines halves.
// x-writes and cat-reads are non-temporal so table rows keep the Infinity Cache.
__global__ __launch_bounds__(256) void embed_bag(
    const float* __restrict__ tables, const int* __restrict__ cat,
    unsigned short* __restrict__ x)
{
    int wid  = blockIdx.x * 4 + (threadIdx.x >> 6);   // t-major bag id = t*B + b
    int lane = threadIdx.x & 63;
    int t = wid >> 14;            // wid / BB
    int b = wid & (BB - 1);       // wid % BB
    const int* ip = cat + ((size_t)b * TT + t) * NN;
    const float* tbase = tables + (size_t)t * RR * DD;
    int half = lane >> 5;         // 0: even-index rows, 1: odd-index rows
    int l5   = lane & 31;         // d-quad: covers d = 4*l5 .. 4*l5+3
    f32x4 acc = {0.f, 0.f, 0.f, 0.f};
    #pragma unroll
    for (int n2 = 0; n2 < 5; n2++) {
        int r = __builtin_nontemporal_load(ip + 2 * n2 + half);
        f32x4 v = *(const f32x4*)(tbase + (size_t)r * DD + l5 * 4);
        acc += v;
    }
    float t0 = acc[0] + __shfl_xor(acc[0], 32, 64);
    float t1 = acc[1] + __shfl_xor(acc[1], 32, 64);
    float t2 = acc[2] + __shfl_xor(acc[2], 32, 64);
    float t3 = acc[3] + __shfl_xor(acc[3], 32, 64);
    if (half == 0) {
        u32x2 pk;
        pk[0] = (unsigned int)f2bf(t0) | ((unsigned int)f2bf(t1) << 16);
        pk[1] = (unsigned int)f2bf(t2) | ((unsigned int)f2bf(t3) << 16);
        __builtin_nontemporal_store(pk, (u32x2*)(x + (size_t)b * KP0 + t * DD + l5 * 4));
    }
}

// ---------------- numerical features + zero pad into x cols [3328,3392) ----------------
__global__ __launch_bounds__(256) void num_fill(
    const float* __restrict__ numerical, unsigned short* __restrict__ x)
{
    int b    = blockIdx.x * 4 + (threadIdx.x >> 6);
    int lane = threadIdx.x & 63;
    unsigned short v = 0;
    if (lane < NUMF) v = f2bf(numerical[b * NUMF + lane]);
    __builtin_nontemporal_store(v, x + (size_t)b * KP0 + TT * DD + lane);
}

// ---------------- bf16 MFMA GEMM: C[M][N] = relu(A[M][K] @ Bt[N][K]^T + bias) ----------
// 128x128 tile, BK=64, 256 threads (4 waves, 2x2), m97-style global_load_lds staging.
// Block index XCD-swizzled (bijective, grid%8==0) so one XCD's L2 reuses one A-panel.
__device__ __forceinline__ void stage_tile(
    const unsigned short* __restrict__ src,   // base already offset by row0*K
    unsigned short* lds, int K, int k0, int tid)
{
    #pragma unroll
    for (int j = 0; j < 4; j++) {
        int ch = j * 256 + tid;                       // chunk 0..1023, 16B each
        const unsigned short* g = src + (size_t)(ch >> 3) * K + k0 + (ch & 7) * 8;
        gload_lds16(g, lds + (size_t)(j * 256 + (tid & 192)) * 8);
    }
}

__global__ __launch_bounds__(256) void gemm_bias_relu(
    const unsigned short* __restrict__ A,    // [M][K] bf16
    const unsigned short* __restrict__ Bt,   // [N][K] bf16 (pre-transposed weight)
    const float* __restrict__ bias,          // [N]
    unsigned short* __restrict__ C,          // [M][N] bf16
    int M, int N, int K, int do_relu)
{
    __shared__ __align__(16) unsigned short As[128 * 64];
    __shared__ __align__(16) unsigned short Bs[128 * 64];

    const int tid  = threadIdx.x;
    const int lane = tid & 63;
    const int w    = tid >> 6;
    const int wm   = w >> 1, wn = w & 1;

    // XCD-aware bijective swizzle of the linear block id (grid.x*grid.y % 8 == 0)
    int nwg  = gridDim.x * gridDim.y;
    int orig = blockIdx.y * gridDim.x + blockIdx.x;
    int cpx  = nwg >> 3;
    int swz  = (orig & 7) * cpx + (orig >> 3);
    int bx   = swz % gridDim.x;
    int by   = swz / gridDim.x;
    const int m0 = by * 128, n0 = bx * 128;

    f32x4 acc[4][4];
    #pragma unroll
    for (int i = 0; i < 4; i++)
        #pragma unroll
        for (int j = 0; j < 4; j++) {
            f32x4 z = {0.f, 0.f, 0.f, 0.f};
            acc[i][j] = z;
        }

    const unsigned short* Abase = A  + (size_t)m0 * K;
    const unsigned short* Bbase = Bt + (size_t)n0 * K;

    for (int k0 = 0; k0 < K; k0 += 64) {
        stage_tile(Abase, As, K, k0, tid);
        stage_tile(Bbase, Bs, K, k0, tid);
        __syncthreads();
        #pragma unroll
        for (int kk = 0; kk < 2; kk++) {
            bf16x8 af[4], bfv[4];
            #pragma unroll
            for (int mi = 0; mi < 4; mi++) {
                int off = (wm * 64 + mi * 16 + (lane & 15)) * 64 + kk * 32 + (lane >> 4) * 8;
                af[mi] = *(const bf16x8*)(As + off);
            }
            #pragma unroll
            for (int ni = 0; ni < 4; ni++) {
                int off = (wn * 64 + ni * 16 + (lane & 15)) * 64 + kk * 32 + (lane >> 4) * 8;
                bfv[ni] = *(const bf16x8*)(Bs + off);
            }
            #pragma unroll
            for (int mi = 0; mi < 4; mi++)
                #pragma unroll
                for (int ni = 0; ni < 4; ni++)
                    acc[mi][ni] = __builtin_amdgcn_mfma_f32_16x16x32_bf16(
                        af[mi], bfv[ni], acc[mi][ni], 0, 0, 0);
        }
        __syncthreads();
    }

    // epilogue: bias + relu + bf16 store.  C/D map: col=lane&15, row=4*(lane>>4)+j
    #pragma unroll
    for (int mi = 0; mi < 4; mi++) {
        int row_base = m0 + wm * 64 + mi * 16 + (lane >> 4) * 4;
        #pragma unroll
        for (int ni = 0; ni < 4; ni++) {
            int col = n0 + wn * 64 + ni * 16 + (lane & 15);
            float bv = bias[col];
            #pragma unroll
            for (int j = 0; j < 4; j++) {
                float v = acc[mi][ni][j] + bv;
                if (do_relu) v = v > 0.f ? v : 0.f;
                C[(size_t)(row_base + j) * N + col] = f2bf(v);
            }
        }
    }
}

// ---------------- final layer: out[b] = h3[b][:256] . W3 + b3 (one wave per row) -------
__global__ __launch_bounds__(256) void final_dot(
    const unsigned short* __restrict__ h3, const float* __restrict__ W3,
    const float* __restrict__ b3, float* __restrict__ out)
{
    int b    = blockIdx.x * 4 + (threadIdx.x >> 6);
    int lane = threadIdx.x & 63;
    uint2 u = *(const uint2*)(h3 + (size_t)b * 256 + lane * 4);
    float f0 = __uint_as_float((u.x & 0xffffu) << 16);
    float f1 = __uint_as_float(u.x & 0xffff0000u);
    float f2 = __uint_as_float((u.y & 0xffffu) << 16);
    float f3 = __uint_as_float(u.y & 0xffff0000u);
    float4 wv = *(const float4*)(W3 + lane * 4);
    float s = f0 * wv.x + f1 * wv.y + f2 * wv.z + f3 * wv.w;
    #pragma unroll
    for (int off = 32; off > 0; off >>= 1) s += __shfl_down(s, off, 64);
    if (lane == 0) out[b] = s + b3[0];
}

extern "C" void kernel_launch(void* const* d_in, const int* in_sizes, int n_in,
                              void* d_out, int out_size, void* d_ws, size_t ws_size,
                              hipStream_t stream)
{
    const float* numerical = (const float*)d_in[0];
    const int*   cat       = (const int*)d_in[1];
    const float* tables    = (const float*)d_in[2];
    const float* W0 = (const float*)d_in[3];
    const float* b0 = (const float*)d_in[4];
    const float* W1 = (const float*)d_in[5];
    const float* b1 = (const float*)d_in[6];
    const float* W2 = (const float*)d_in[7];
    const float* b2 = (const float*)d_in[8];
    const float* W3 = (const float*)d_in[9];
    const float* b3 = (const float*)d_in[10];
    float* out = (float*)d_out;

    // workspace layout (bf16 elements); h2/h3 alias x (dead after L0)
    unsigned short* x   = (unsigned short*)d_ws;            // [16384][3392]
    unsigned short* w0t = x   + (size_t)BB * KP0;           // [1024][3392]
    unsigned short* w1t = w0t + (size_t)1024 * KP0;         // [512][1024]
    unsigned short* w2t = w1t + (size_t)512 * 1024;         // [256][512]
    unsigned short* h1  = w2t + (size_t)256 * 512;          // [16384][1024]
    unsigned short* h2  = x;                                // [16384][512]
    unsigned short* h3  = x   + (size_t)BB * 512;           // [16384][256]

    transpose_cvt<<<dim3(53, 16), 256, 0, stream>>>(W0, w0t, TT * DD + NUMF, KP0, 1024);
    transpose_cvt<<<dim3(16, 8),  256, 0, stream>>>(W1, w1t, 1024, 1024, 512);
    transpose_cvt<<<dim3(8, 4),   256, 0, stream>>>(W2, w2t, 512, 512, 256);

    embed_bag<<<dim3(BB * TT / 4), 256, 0, stream>>>(tables, cat, x);
    num_fill <<<dim3(BB / 4),      256, 0, stream>>>(numerical, x);

    gemm_bias_relu<<<dim3(8, 128), 256, 0, stream>>>(x,  w0t, b0, h1, BB, 1024, KP0, 1);
    gemm_bias_relu<<<dim3(4, 128), 256, 0, stream>>>(h1, w1t, b1, h2, BB, 512, 1024, 1);
    gemm_bias_relu<<<dim3(2, 128), 256, 0, stream>>>(h2, w2t, b2, h3, BB, 256, 512, 1);

    final_dot<<<dim3(BB / 4), 256, 0, stream>>>(h3, W3, b3, out);
}

// Round 4
// 516.105 us; speedup vs baseline: 1.2870x; 1.1270x over previous
//
#include <hip/hip_runtime.h>

// Problem constants
#define TT   26
#define RR   100000
#define DD   128
#define NN   10
#define BB   16384
#define NUMF 13
#define KP0  3392   // T*D+NUM = 3341 padded to 53*64 (also /32 = 106)

typedef __bf16 bf16x8 __attribute__((ext_vector_type(8)));
typedef float  f32x4  __attribute__((ext_vector_type(4)));
typedef unsigned int u32x2 __attribute__((ext_vector_type(2)));

__device__ __forceinline__ unsigned short f2bf(float f) {
    unsigned int u = __float_as_uint(f);
    u += 0x7FFFu + ((u >> 16) & 1u);          // round-to-nearest-even
    return (unsigned short)(u >> 16);
}

__device__ __forceinline__ void gload_lds16(const void* g, void* l) {
    __builtin_amdgcn_global_load_lds(
        (const __attribute__((address_space(1))) void*)g,
        (__attribute__((address_space(3))) void*)l, 16, 0, 0);
}

// ---------------- weight transpose + f32->bf16 (W[K][N] -> Wt[N][KPad]) ----------------
__global__ __launch_bounds__(256) void transpose_cvt(
    const float* __restrict__ in, unsigned short* __restrict__ out,
    int Kin, int KPad, int N)
{
    __shared__ float tile[64][65];
    int k0 = blockIdx.x * 64;
    int n0 = blockIdx.y * 64;
    int c  = threadIdx.x & 63;
    int rr = threadIdx.x >> 6;          // 0..3
    #pragma unroll
    for (int r = rr; r < 64; r += 4) {
        int k = k0 + r, n = n0 + c;
        float v = 0.f;
        if (k < Kin && n < N) v = in[(size_t)k * N + n];
        tile[r][c] = v;
    }
    __syncthreads();
    #pragma unroll
    for (int r = rr; r < 64; r += 4) {
        int n = n0 + r, kp = k0 + c;
        if (n < N && kp < KPad)
            out[(size_t)n * KPad + kp] = f2bf(tile[c][r]);
    }
}

// ---------------- embedding bag: one wave per (t,b), TABLE-MAJOR for LLC locality -------
__global__ __launch_bounds__(256) void embed_bag(
    const float* __restrict__ tables, const int* __restrict__ cat,
    unsigned short* __restrict__ x)
{
    int wid  = blockIdx.x * 4 + (threadIdx.x >> 6);   // t-major bag id = t*B + b
    int lane = threadIdx.x & 63;
    int t = wid >> 14;            // wid / BB
    int b = wid & (BB - 1);       // wid % BB
    const int* ip = cat + ((size_t)b * TT + t) * NN;
    const float* tbase = tables + (size_t)t * RR * DD;
    int half = lane >> 5;         // 0: even-index rows, 1: odd-index rows
    int l5   = lane & 31;         // d-quad: covers d = 4*l5 .. 4*l5+3
    f32x4 acc = {0.f, 0.f, 0.f, 0.f};
    #pragma unroll
    for (int n2 = 0; n2 < 5; n2++) {
        int r = __builtin_nontemporal_load(ip + 2 * n2 + half);
        f32x4 v = *(const f32x4*)(tbase + (size_t)r * DD + l5 * 4);
        acc += v;
    }
    float t0 = acc[0] + __shfl_xor(acc[0], 32, 64);
    float t1 = acc[1] + __shfl_xor(acc[1], 32, 64);
    float t2 = acc[2] + __shfl_xor(acc[2], 32, 64);
    float t3 = acc[3] + __shfl_xor(acc[3], 32, 64);
    if (half == 0) {
        u32x2 pk;
        pk[0] = (unsigned int)f2bf(t0) | ((unsigned int)f2bf(t1) << 16);
        pk[1] = (unsigned int)f2bf(t2) | ((unsigned int)f2bf(t3) << 16);
        __builtin_nontemporal_store(pk, (u32x2*)(x + (size_t)b * KP0 + t * DD + l5 * 4));
    }
}

// ---------------- numerical features + zero pad into x cols [3328,3392) ----------------
__global__ __launch_bounds__(256) void num_fill(
    const float* __restrict__ numerical, unsigned short* __restrict__ x)
{
    int b    = blockIdx.x * 4 + (threadIdx.x >> 6);
    int lane = threadIdx.x & 63;
    unsigned short v = 0;
    if (lane < NUMF) v = f2bf(numerical[b * NUMF + lane]);
    __builtin_nontemporal_store(v, x + (size_t)b * KP0 + TT * DD + lane);
}

// ======================= 256x256 8-phase-style MFMA GEMM (L0) ==========================
// BM=BN=256, rotation unit = half-K tile (BK=32) over 4 LDS buffers (4x32KB=128KB).
// Computing half-tile h reads buf h%4 while staging h+2 into buf (h+2)%4 -> disjoint,
// so counted vmcnt(4) at the boundary is race-free by construction (each wave's own
// h+1 stages landed before the barrier -> collectively whole buffer landed).
// LDS layout per buffer: A[256 rows][32K] then B[256 rows][32K], stored row-pair
// interleaved: byte = (r>>1)*128 + (r&1)*64 + k16*16 -> 16-lane column reads are
// 2-way bank aliased (free), no XOR swizzle needed; gload_lds dest stays linear.
#define G_BUFB 32768

__global__ __launch_bounds__(512, 2) void gemm256(
    const unsigned short* __restrict__ A,    // [M][K] bf16
    const unsigned short* __restrict__ Bt,   // [N][K] bf16
    const float* __restrict__ bias,
    unsigned short* __restrict__ C,          // [M][N] bf16
    int M, int N, int K, int do_relu)
{
    extern __shared__ __align__(16) char lds[];
    const int tid  = threadIdx.x;
    const int lane = tid & 63;
    const int w    = tid >> 6;
    const int wm   = w >> 2, wn = w & 3;      // 2 x 4 waves, wave-tile 128x64

    // XCD-aware bijective swizzle (nwg % 8 == 0)
    int nwg  = gridDim.x * gridDim.y;
    int orig = blockIdx.y * gridDim.x + blockIdx.x;
    int cpx  = nwg >> 3;
    int swz  = (orig & 7) * cpx + (orig >> 3);
    int bx   = swz % gridDim.x;
    int by   = swz / gridDim.x;
    const int m0 = by * 256, n0 = bx * 256;

    const int NT = K >> 5;                    // number of half-K (32) tiles

    f32x4 acc[8][4];
    #pragma unroll
    for (int i = 0; i < 8; i++)
        #pragma unroll
        for (int j = 0; j < 4; j++) {
            f32x4 z = {0.f, 0.f, 0.f, 0.f};
            acc[i][j] = z;
        }

    // stage unit u of half-tile h: u=0,1 -> A rows [0,128),[128,256); u=2,3 -> B rows.
    // thread tid handles 16B slot i = (u&1)*512 + tid of the 16KB region:
    //   row = 2*(i>>3) + ((i>>2)&1), k16 = i&3  (matches interleaved read layout)
    auto stage_unit = [&](int h, int u) {
        int i    = ((u & 1) << 9) + tid;
        int row  = 2 * (i >> 3) + ((i >> 2) & 1);
        int col8 = i & 3;
        const unsigned short* base = (u < 2)
            ? (A  + (size_t)(m0 + row) * K)
            : (Bt + (size_t)(n0 + row) * K);
        const unsigned short* g = base + (h << 5) + col8 * 8;
        char* l = lds + (size_t)(h & 3) * G_BUFB + ((u >> 1) << 14) + ((u & 1) << 13)
                      + ((tid >> 6) << 10);
        gload_lds16(g, l);
    };

    // prologue: stage half-tiles 0 and 1 (4 loads each), wait for tile 0
    #pragma unroll
    for (int u = 0; u < 4; u++) stage_unit(0, u);
    #pragma unroll
    for (int u = 0; u < 4; u++) stage_unit(1, u);
    asm volatile("s_waitcnt vmcnt(4)" ::: "memory");
    __builtin_amdgcn_s_barrier();

    for (int h = 0; h < NT; ++h) {
        const char* bufR = lds + (size_t)(h & 3) * G_BUFB;
        const bool  do_stage = (h + 2) < NT;

        bf16x8 bfr[4];
        #pragma unroll
        for (int p = 0; p < 4; p++) {          // 4 phases, phase p: m-frags 2p, 2p+1
            if (do_stage) stage_unit(h + 2, p);
            if (p == 0) {                      // B frags for the whole half-tile
                #pragma unroll
                for (int nf = 0; nf < 4; nf++) {
                    int r = wn * 64 + nf * 16 + (lane & 15);
                    bfr[nf] = *(const bf16x8*)(bufR + 16384 + ((r >> 1) << 7)
                                               + ((r & 1) << 6) + ((lane >> 4) << 4));
                }
            }
            bf16x8 afr[2];
            #pragma unroll
            for (int q = 0; q < 2; q++) {
                int r = wm * 128 + (2 * p + q) * 16 + (lane & 15);
                afr[q] = *(const bf16x8*)(bufR + ((r >> 1) << 7)
                                          + ((r & 1) << 6) + ((lane >> 4) << 4));
            }
            asm volatile("s_waitcnt lgkmcnt(0)" ::: "memory");
            __builtin_amdgcn_sched_barrier(0);
            __builtin_amdgcn_s_setprio(1);
            #pragma unroll
            for (int q = 0; q < 2; q++)
                #pragma unroll
                for (int nf = 0; nf < 4; nf++)
                    acc[2 * p + q][nf] = __builtin_amdgcn_mfma_f32_16x16x32_bf16(
                        afr[q], bfr[nf], acc[2 * p + q][nf], 0, 0, 0);
            __builtin_amdgcn_s_setprio(0);
            if (p < 3) __builtin_amdgcn_s_barrier();
        }
        // boundary: own h+1 stages must be landed before any wave reads them next tile
        if (do_stage) asm volatile("s_waitcnt vmcnt(4)" ::: "memory");
        else          asm volatile("s_waitcnt vmcnt(0)" ::: "memory");
        __builtin_amdgcn_s_barrier();
    }

    // epilogue: bias + relu + bf16 store.  C/D map: col=lane&15, row=4*(lane>>4)+j
    #pragma unroll
    for (int mf = 0; mf < 8; mf++) {
        int row_base = m0 + wm * 128 + mf * 16 + (lane >> 4) * 4;
        #pragma unroll
        for (int nf = 0; nf < 4; nf++) {
            int col = n0 + wn * 64 + nf * 16 + (lane & 15);
            float bv = bias[col];
            #pragma unroll
            for (int j = 0; j < 4; j++) {
                float v = acc[mf][nf][j] + bv;
                if (do_relu) v = v > 0.f ? v : 0.f;
                C[(size_t)(row_base + j) * N + col] = f2bf(v);
            }
        }
    }
}

// ---------------- 128x128 MFMA GEMM (L1/L2): m97-style 2-barrier structure ------------
__device__ __forceinline__ void stage_tile(
    const unsigned short* __restrict__ src,
    unsigned short* lds, int K, int k0, int tid)
{
    #pragma unroll
    for (int j = 0; j < 4; j++) {
        int ch = j * 256 + tid;
        const unsigned short* g = src + (size_t)(ch >> 3) * K + k0 + (ch & 7) * 8;
        gload_lds16(g, lds + (size_t)(j * 256 + (tid & 192)) * 8);
    }
}

__global__ __launch_bounds__(256) void gemm_bias_relu(
    const unsigned short* __restrict__ A,
    const unsigned short* __restrict__ Bt,
    const float* __restrict__ bias,
    unsigned short* __restrict__ C,
    int M, int N, int K, int do_relu)
{
    __shared__ __align__(16) unsigned short As[128 * 64];
    __shared__ __align__(16) unsigned short Bs[128 * 64];

    const int tid  = threadIdx.x;
    const int lane = tid & 63;
    const int w    = tid >> 6;
    const int wm   = w >> 1, wn = w & 1;

    int nwg  = gridDim.x * gridDim.y;
    int orig = blockIdx.y * gridDim.x + blockIdx.x;
    int cpx  = nwg >> 3;
    int swz  = (orig & 7) * cpx + (orig >> 3);
    int bx   = swz % gridDim.x;
    int by   = swz / gridDim.x;
    const int m0 = by * 128, n0 = bx * 128;

    f32x4 acc[4][4];
    #pragma unroll
    for (int i = 0; i < 4; i++)
        #pragma unroll
        for (int j = 0; j < 4; j++) {
            f32x4 z = {0.f, 0.f, 0.f, 0.f};
            acc[i][j] = z;
        }

    const unsigned short* Abase = A  + (size_t)m0 * K;
    const unsigned short* Bbase = Bt + (size_t)n0 * K;

    for (int k0 = 0; k0 < K; k0 += 64) {
        stage_tile(Abase, As, K, k0, tid);
        stage_tile(Bbase, Bs, K, k0, tid);
        __syncthreads();
        #pragma unroll
        for (int kk = 0; kk < 2; kk++) {
            bf16x8 af[4], bfv[4];
            #pragma unroll
            for (int mi = 0; mi < 4; mi++) {
                int off = (wm * 64 + mi * 16 + (lane & 15)) * 64 + kk * 32 + (lane >> 4) * 8;
                af[mi] = *(const bf16x8*)(As + off);
            }
            #pragma unroll
            for (int ni = 0; ni < 4; ni++) {
                int off = (wn * 64 + ni * 16 + (lane & 15)) * 64 + kk * 32 + (lane >> 4) * 8;
                bfv[ni] = *(const bf16x8*)(Bs + off);
            }
            #pragma unroll
            for (int mi = 0; mi < 4; mi++)
                #pragma unroll
                for (int ni = 0; ni < 4; ni++)
                    acc[mi][ni] = __builtin_amdgcn_mfma_f32_16x16x32_bf16(
                        af[mi], bfv[ni], acc[mi][ni], 0, 0, 0);
        }
        __syncthreads();
    }

    #pragma unroll
    for (int mi = 0; mi < 4; mi++) {
        int row_base = m0 + wm * 64 + mi * 16 + (lane >> 4) * 4;
        #pragma unroll
        for (int ni = 0; ni < 4; ni++) {
            int col = n0 + wn * 64 + ni * 16 + (lane & 15);
            float bv = bias[col];
            #pragma unroll
            for (int j = 0; j < 4; j++) {
                float v = acc[mi][ni][j] + bv;
                if (do_relu) v = v > 0.f ? v : 0.f;
                C[(size_t)(row_base + j) * N + col] = f2bf(v);
            }
        }
    }
}

// ---------------- final layer: out[b] = h3[b][:256] . W3 + b3 (one wave per row) -------
__global__ __launch_bounds__(256) void final_dot(
    const unsigned short* __restrict__ h3, const float* __restrict__ W3,
    const float* __restrict__ b3, float* __restrict__ out)
{
    int b    = blockIdx.x * 4 + (threadIdx.x >> 6);
    int lane = threadIdx.x & 63;
    uint2 u = *(const uint2*)(h3 + (size_t)b * 256 + lane * 4);
    float f0 = __uint_as_float((u.x & 0xffffu) << 16);
    float f1 = __uint_as_float(u.x & 0xffff0000u);
    float f2 = __uint_as_float((u.y & 0xffffu) << 16);
    float f3 = __uint_as_float(u.y & 0xffff0000u);
    float4 wv = *(const float4*)(W3 + lane * 4);
    float s = f0 * wv.x + f1 * wv.y + f2 * wv.z + f3 * wv.w;
    #pragma unroll
    for (int off = 32; off > 0; off >>= 1) s += __shfl_down(s, off, 64);
    if (lane == 0) out[b] = s + b3[0];
}

extern "C" void kernel_launch(void* const* d_in, const int* in_sizes, int n_in,
                              void* d_out, int out_size, void* d_ws, size_t ws_size,
                              hipStream_t stream)
{
    const float* numerical = (const float*)d_in[0];
    const int*   cat       = (const int*)d_in[1];
    const float* tables    = (const float*)d_in[2];
    const float* W0 = (const float*)d_in[3];
    const float* b0 = (const float*)d_in[4];
    const float* W1 = (const float*)d_in[5];
    const float* b1 = (const float*)d_in[6];
    const float* W2 = (const float*)d_in[7];
    const float* b2 = (const float*)d_in[8];
    const float* W3 = (const float*)d_in[9];
    const float* b3 = (const float*)d_in[10];
    float* out = (float*)d_out;

    // workspace layout (bf16 elements); h2/h3 alias x (dead after L0)
    unsigned short* x   = (unsigned short*)d_ws;            // [16384][3392]
    unsigned short* w0t = x   + (size_t)BB * KP0;           // [1024][3392]
    unsigned short* w1t = w0t + (size_t)1024 * KP0;         // [512][1024]
    unsigned short* w2t = w1t + (size_t)512 * 1024;         // [256][512]
    unsigned short* h1  = w2t + (size_t)256 * 512;          // [16384][1024]
    unsigned short* h2  = x;                                // [16384][512]
    unsigned short* h3  = x   + (size_t)BB * 512;           // [16384][256]

    (void)hipFuncSetAttribute((const void*)gemm256,
                              hipFuncAttributeMaxDynamicSharedMemorySize, 131072);

    transpose_cvt<<<dim3(53, 16), 256, 0, stream>>>(W0, w0t, TT * DD + NUMF, KP0, 1024);
    transpose_cvt<<<dim3(16, 8),  256, 0, stream>>>(W1, w1t, 1024, 1024, 512);
    transpose_cvt<<<dim3(8, 4),   256, 0, stream>>>(W2, w2t, 512, 512, 256);

    embed_bag<<<dim3(BB * TT / 4), 256, 0, stream>>>(tables, cat, x);
    num_fill <<<dim3(BB / 4),      256, 0, stream>>>(numerical, x);

    gemm256<<<dim3(1024 / 256, BB / 256), 512, 131072, stream>>>(
        x, w0t, b0, h1, BB, 1024, KP0, 1);
    gemm_bias_relu<<<dim3(4, 128), 256, 0, stream>>>(h1, w1t, b1, h2, BB, 512, 1024, 1);
    gemm_bias_relu<<<dim3(2, 128), 256, 0, stream>>>(h2, w2t, b2, h3, BB, 256, 512, 1);

    final_dot<<<dim3(BB / 4), 256, 0, stream>>>(h3, W3, b3, out);
}

// Round 5
// 495.561 us; speedup vs baseline: 1.3403x; 1.0415x over previous
//
#include <hip/hip_runtime.h>

// Problem constants
#define TT   26
#define RR   100000
#define DD   128
#define NN   10
#define BB   16384
#define NUMF 13
#define KP0  3392   // T*D+NUM = 3341 padded to 53*64 (also /32 = 106)

typedef __bf16 bf16x8 __attribute__((ext_vector_type(8)));
typedef float  f32x4  __attribute__((ext_vector_type(4)));
typedef unsigned int u32x2 __attribute__((ext_vector_type(2)));

__device__ __forceinline__ unsigned short f2bf(float f) {
    unsigned int u = __float_as_uint(f);
    u += 0x7FFFu + ((u >> 16) & 1u);          // round-to-nearest-even
    return (unsigned short)(u >> 16);
}

__device__ __forceinline__ void gload_lds16(const void* g, void* l) {
    __builtin_amdgcn_global_load_lds(
        (const __attribute__((address_space(1))) void*)g,
        (__attribute__((address_space(3))) void*)l, 16, 0, 0);
}

// -------- fused weight transposes + f32->bf16 (W[K][N] -> Wt[N][KPad]), one launch ------
__global__ __launch_bounds__(256) void transpose_all(
    const float* __restrict__ W0, const float* __restrict__ W1,
    const float* __restrict__ W2,
    unsigned short* __restrict__ w0t, unsigned short* __restrict__ w1t,
    unsigned short* __restrict__ w2t)
{
    const float* in; unsigned short* out; int Kin, KPad, N;
    int z = blockIdx.z;
    if (z == 0)      { in = W0; out = w0t; Kin = TT*DD+NUMF; KPad = KP0;  N = 1024; }
    else if (z == 1) { in = W1; out = w1t; Kin = 1024;       KPad = 1024; N = 512;
                       if (blockIdx.x >= 16 || blockIdx.y >= 8) return; }
    else             { in = W2; out = w2t; Kin = 512;        KPad = 512;  N = 256;
                       if (blockIdx.x >= 8  || blockIdx.y >= 4) return; }

    __shared__ float tile[64][65];
    int k0 = blockIdx.x * 64;
    int n0 = blockIdx.y * 64;
    int c  = threadIdx.x & 63;
    int rr = threadIdx.x >> 6;          // 0..3
    #pragma unroll
    for (int r = rr; r < 64; r += 4) {
        int k = k0 + r, n = n0 + c;
        float v = 0.f;
        if (k < Kin && n < N) v = in[(size_t)k * N + n];
        tile[r][c] = v;
    }
    __syncthreads();
    #pragma unroll
    for (int r = rr; r < 64; r += 4) {
        int n = n0 + r, kp = k0 + c;
        if (n < N && kp < KPad)
            out[(size_t)n * KPad + kp] = f2bf(tile[c][r]);
    }
}

// ---------------- embedding bag (table-major) + fused numerical-feature fill ------------
// Bags: one wave per (t,b), t-major so the active 51MB table stays LLC-resident.
// Two rows gathered per instruction (lanes 0-31 even row, 32-63 odd row, 16B/lane ->
// 5x global_load_dwordx4), one shfl_xor(32) combine. Blocks past the bag range fill
// the numerical columns [3328,3392).
__global__ __launch_bounds__(256) void embed_bag(
    const float* __restrict__ tables, const int* __restrict__ cat,
    const float* __restrict__ numerical, unsigned short* __restrict__ x)
{
    int wid  = blockIdx.x * 4 + (threadIdx.x >> 6);
    int lane = threadIdx.x & 63;
    if (wid >= BB * TT) {                      // numerical fill path (whole block)
        int b = wid - BB * TT;
        unsigned short v = 0;
        if (lane < NUMF) v = f2bf(numerical[b * NUMF + lane]);
        __builtin_nontemporal_store(v, x + (size_t)b * KP0 + TT * DD + lane);
        return;
    }
    int t = wid >> 14;            // wid / BB
    int b = wid & (BB - 1);       // wid % BB
    const int* ip = cat + ((size_t)b * TT + t) * NN;
    const float* tbase = tables + (size_t)t * RR * DD;
    int half = lane >> 5;         // 0: even-index rows, 1: odd-index rows
    int l5   = lane & 31;         // d-quad: covers d = 4*l5 .. 4*l5+3
    f32x4 acc = {0.f, 0.f, 0.f, 0.f};
    #pragma unroll
    for (int n2 = 0; n2 < 5; n2++) {
        int r = __builtin_nontemporal_load(ip + 2 * n2 + half);
        f32x4 v = *(const f32x4*)(tbase + (size_t)r * DD + l5 * 4);
        acc += v;
    }
    float t0 = acc[0] + __shfl_xor(acc[0], 32, 64);
    float t1 = acc[1] + __shfl_xor(acc[1], 32, 64);
    float t2 = acc[2] + __shfl_xor(acc[2], 32, 64);
    float t3 = acc[3] + __shfl_xor(acc[3], 32, 64);
    if (half == 0) {
        u32x2 pk;
        pk[0] = (unsigned int)f2bf(t0) | ((unsigned int)f2bf(t1) << 16);
        pk[1] = (unsigned int)f2bf(t2) | ((unsigned int)f2bf(t3) << 16);
        __builtin_nontemporal_store(pk, (u32x2*)(x + (size_t)b * KP0 + t * DD + l5 * 4));
    }
}

// ======================= 256x256 4-phase counted-vmcnt MFMA GEMM =======================
// BM=BN=256, rotation unit = half-K tile (BK=32) over 4 LDS buffers (4x32KB=128KB).
// Computing half-tile h reads buf h%4 while staging h+2 into buf (h+2)%4 -> disjoint,
// so counted vmcnt(4) at the boundary is race-free by construction.
// LDS layout per buffer: A[256 rows][32K] then B[256 rows][32K], row-pair interleaved:
// byte = (r>>1)*128 + (r&1)*64 + k16*16 -> column reads 2-way bank aliased (free).
#define G_BUFB 32768

__global__ __launch_bounds__(512, 2) void gemm256(
    const unsigned short* __restrict__ A,    // [M][K] bf16
    const unsigned short* __restrict__ Bt,   // [N][K] bf16
    const float* __restrict__ bias,
    unsigned short* __restrict__ C,          // [M][N] bf16
    int M, int N, int K, int do_relu)
{
    extern __shared__ __align__(16) char lds[];
    const int tid  = threadIdx.x;
    const int lane = tid & 63;
    const int w    = tid >> 6;
    const int wm   = w >> 2, wn = w & 3;      // 2 x 4 waves, wave-tile 128x64

    // XCD-aware bijective swizzle (nwg % 8 == 0)
    int nwg  = gridDim.x * gridDim.y;
    int orig = blockIdx.y * gridDim.x + blockIdx.x;
    int cpx  = nwg >> 3;
    int swz  = (orig & 7) * cpx + (orig >> 3);
    int bx   = swz % gridDim.x;
    int by   = swz / gridDim.x;
    const int m0 = by * 256, n0 = bx * 256;

    const int NT = K >> 5;                    // number of half-K (32) tiles

    f32x4 acc[8][4];
    #pragma unroll
    for (int i = 0; i < 8; i++)
        #pragma unroll
        for (int j = 0; j < 4; j++) {
            f32x4 z = {0.f, 0.f, 0.f, 0.f};
            acc[i][j] = z;
        }

    auto stage_unit = [&](int h, int u) {
        int i    = ((u & 1) << 9) + tid;
        int row  = 2 * (i >> 3) + ((i >> 2) & 1);
        int col8 = i & 3;
        const unsigned short* base = (u < 2)
            ? (A  + (size_t)(m0 + row) * K)
            : (Bt + (size_t)(n0 + row) * K);
        const unsigned short* g = base + (h << 5) + col8 * 8;
        char* l = lds + (size_t)(h & 3) * G_BUFB + ((u >> 1) << 14) + ((u & 1) << 13)
                      + ((tid >> 6) << 10);
        gload_lds16(g, l);
    };

    #pragma unroll
    for (int u = 0; u < 4; u++) stage_unit(0, u);
    #pragma unroll
    for (int u = 0; u < 4; u++) stage_unit(1, u);
    asm volatile("s_waitcnt vmcnt(4)" ::: "memory");
    __builtin_amdgcn_s_barrier();

    for (int h = 0; h < NT; ++h) {
        const char* bufR = lds + (size_t)(h & 3) * G_BUFB;
        const bool  do_stage = (h + 2) < NT;

        bf16x8 bfr[4];
        #pragma unroll
        for (int p = 0; p < 4; p++) {          // phase p computes m-frags 2p, 2p+1
            if (do_stage) stage_unit(h + 2, p);
            if (p == 0) {
                #pragma unroll
                for (int nf = 0; nf < 4; nf++) {
                    int r = wn * 64 + nf * 16 + (lane & 15);
                    bfr[nf] = *(const bf16x8*)(bufR + 16384 + ((r >> 1) << 7)
                                               + ((r & 1) << 6) + ((lane >> 4) << 4));
                }
            }
            bf16x8 afr[2];
            #pragma unroll
            for (int q = 0; q < 2; q++) {
                int r = wm * 128 + (2 * p + q) * 16 + (lane & 15);
                afr[q] = *(const bf16x8*)(bufR + ((r >> 1) << 7)
                                          + ((r & 1) << 6) + ((lane >> 4) << 4));
            }
            asm volatile("s_waitcnt lgkmcnt(0)" ::: "memory");
            __builtin_amdgcn_sched_barrier(0);
            __builtin_amdgcn_s_setprio(1);
            #pragma unroll
            for (int q = 0; q < 2; q++)
                #pragma unroll
                for (int nf = 0; nf < 4; nf++)
                    acc[2 * p + q][nf] = __builtin_amdgcn_mfma_f32_16x16x32_bf16(
                        afr[q], bfr[nf], acc[2 * p + q][nf], 0, 0, 0);
            __builtin_amdgcn_s_setprio(0);
            if (p < 3) __builtin_amdgcn_s_barrier();
        }
        if (do_stage) asm volatile("s_waitcnt vmcnt(4)" ::: "memory");
        else          asm volatile("s_waitcnt vmcnt(0)" ::: "memory");
        __builtin_amdgcn_s_barrier();
    }

    // epilogue: bias + relu + bf16 store.  C/D map: col=lane&15, row=4*(lane>>4)+j
    #pragma unroll
    for (int mf = 0; mf < 8; mf++) {
        int row_base = m0 + wm * 128 + mf * 16 + (lane >> 4) * 4;
        #pragma unroll
        for (int nf = 0; nf < 4; nf++) {
            int col = n0 + wn * 64 + nf * 16 + (lane & 15);
            float bv = bias[col];
            #pragma unroll
            for (int j = 0; j < 4; j++) {
                float v = acc[mf][nf][j] + bv;
                if (do_relu) v = v > 0.f ? v : 0.f;
                C[(size_t)(row_base + j) * N + col] = f2bf(v);
            }
        }
    }
}

// ---------------- 128x128 MFMA GEMM (L2): m97-style 2-barrier structure ----------------
__device__ __forceinline__ void stage_tile(
    const unsigned short* __restrict__ src,
    unsigned short* lds, int K, int k0, int tid)
{
    #pragma unroll
    for (int j = 0; j < 4; j++) {
        int ch = j * 256 + tid;
        const unsigned short* g = src + (size_t)(ch >> 3) * K + k0 + (ch & 7) * 8;
        gload_lds16(g, lds + (size_t)(j * 256 + (tid & 192)) * 8);
    }
}

__global__ __launch_bounds__(256) void gemm_bias_relu(
    const unsigned short* __restrict__ A,
    const unsigned short* __restrict__ Bt,
    const float* __restrict__ bias,
    unsigned short* __restrict__ C,
    int M, int N, int K, int do_relu)
{
    __shared__ __align__(16) unsigned short As[128 * 64];
    __shared__ __align__(16) unsigned short Bs[128 * 64];

    const int tid  = threadIdx.x;
    const int lane = tid & 63;
    const int w    = tid >> 6;
    const int wm   = w >> 1, wn = w & 1;

    int nwg  = gridDim.x * gridDim.y;
    int orig = blockIdx.y * gridDim.x + blockIdx.x;
    int cpx  = nwg >> 3;
    int swz  = (orig & 7) * cpx + (orig >> 3);
    int bx   = swz % gridDim.x;
    int by   = swz / gridDim.x;
    const int m0 = by * 128, n0 = bx * 128;

    f32x4 acc[4][4];
    #pragma unroll
    for (int i = 0; i < 4; i++)
        #pragma unroll
        for (int j = 0; j < 4; j++) {
            f32x4 z = {0.f, 0.f, 0.f, 0.f};
            acc[i][j] = z;
        }

    const unsigned short* Abase = A  + (size_t)m0 * K;
    const unsigned short* Bbase = Bt + (size_t)n0 * K;

    for (int k0 = 0; k0 < K; k0 += 64) {
        stage_tile(Abase, As, K, k0, tid);
        stage_tile(Bbase, Bs, K, k0, tid);
        __syncthreads();
        #pragma unroll
        for (int kk = 0; kk < 2; kk++) {
            bf16x8 af[4], bfv[4];
            #pragma unroll
            for (int mi = 0; mi < 4; mi++) {
                int off = (wm * 64 + mi * 16 + (lane & 15)) * 64 + kk * 32 + (lane >> 4) * 8;
                af[mi] = *(const bf16x8*)(As + off);
            }
            #pragma unroll
            for (int ni = 0; ni < 4; ni++) {
                int off = (wn * 64 + ni * 16 + (lane & 15)) * 64 + kk * 32 + (lane >> 4) * 8;
                bfv[ni] = *(const bf16x8*)(Bs + off);
            }
            #pragma unroll
            for (int mi = 0; mi < 4; mi++)
                #pragma unroll
                for (int ni = 0; ni < 4; ni++)
                    acc[mi][ni] = __builtin_amdgcn_mfma_f32_16x16x32_bf16(
                        af[mi], bfv[ni], acc[mi][ni], 0, 0, 0);
        }
        __syncthreads();
    }

    #pragma unroll
    for (int mi = 0; mi < 4; mi++) {
        int row_base = m0 + wm * 64 + mi * 16 + (lane >> 4) * 4;
        #pragma unroll
        for (int ni = 0; ni < 4; ni++) {
            int col = n0 + wn * 64 + ni * 16 + (lane & 15);
            float bv = bias[col];
            #pragma unroll
            for (int j = 0; j < 4; j++) {
                float v = acc[mi][ni][j] + bv;
                if (do_relu) v = v > 0.f ? v : 0.f;
                C[(size_t)(row_base + j) * N + col] = f2bf(v);
            }
        }
    }
}

// ---------------- final layer: out[b] = h3[b][:256] . W3 + b3 (one wave per row) -------
__global__ __launch_bounds__(256) void final_dot(
    const unsigned short* __restrict__ h3, const float* __restrict__ W3,
    const float* __restrict__ b3, float* __restrict__ out)
{
    int b    = blockIdx.x * 4 + (threadIdx.x >> 6);
    int lane = threadIdx.x & 63;
    uint2 u = *(const uint2*)(h3 + (size_t)b * 256 + lane * 4);
    float f0 = __uint_as_float((u.x & 0xffffu) << 16);
    float f1 = __uint_as_float(u.x & 0xffff0000u);
    float f2 = __uint_as_float((u.y & 0xffffu) << 16);
    float f3 = __uint_as_float(u.y & 0xffff0000u);
    float4 wv = *(const float4*)(W3 + lane * 4);
    float s = f0 * wv.x + f1 * wv.y + f2 * wv.z + f3 * wv.w;
    #pragma unroll
    for (int off = 32; off > 0; off >>= 1) s += __shfl_down(s, off, 64);
    if (lane == 0) out[b] = s + b3[0];
}

extern "C" void kernel_launch(void* const* d_in, const int* in_sizes, int n_in,
                              void* d_out, int out_size, void* d_ws, size_t ws_size,
                              hipStream_t stream)
{
    const float* numerical = (const float*)d_in[0];
    const int*   cat       = (const int*)d_in[1];
    const float* tables    = (const float*)d_in[2];
    const float* W0 = (const float*)d_in[3];
    const float* b0 = (const float*)d_in[4];
    const float* W1 = (const float*)d_in[5];
    const float* b1 = (const float*)d_in[6];
    const float* W2 = (const float*)d_in[7];
    const float* b2 = (const float*)d_in[8];
    const float* W3 = (const float*)d_in[9];
    const float* b3 = (const float*)d_in[10];
    float* out = (float*)d_out;

    // workspace layout (bf16 elements); h2/h3 alias x (dead after L0)
    unsigned short* x   = (unsigned short*)d_ws;            // [16384][3392]
    unsigned short* w0t = x   + (size_t)BB * KP0;           // [1024][3392]
    unsigned short* w1t = w0t + (size_t)1024 * KP0;         // [512][1024]
    unsigned short* w2t = w1t + (size_t)512 * 1024;         // [256][512]
    unsigned short* h1  = w2t + (size_t)256 * 512;          // [16384][1024]
    unsigned short* h2  = x;                                // [16384][512]
    unsigned short* h3  = x   + (size_t)BB * 512;           // [16384][256]

    (void)hipFuncSetAttribute((const void*)gemm256,
                              hipFuncAttributeMaxDynamicSharedMemorySize, 131072);

    embed_bag<<<dim3((BB * TT + BB) / 4), 256, 0, stream>>>(tables, cat, numerical, x);
    transpose_all<<<dim3(53, 16, 3), 256, 0, stream>>>(W0, W1, W2, w0t, w1t, w2t);

    gemm256<<<dim3(1024 / 256, BB / 256), 512, 131072, stream>>>(
        x, w0t, b0, h1, BB, 1024, KP0, 1);
    gemm256<<<dim3(512 / 256, BB / 256), 512, 131072, stream>>>(
        h1, w1t, b1, h2, BB, 512, 1024, 1);
    gemm_bias_relu<<<dim3(2, 128), 256, 0, stream>>>(h2, w2t, b2, h3, BB, 256, 512, 1);

    final_dot<<<dim3(BB / 4), 256, 0, stream>>>(h3, W3, b3, out);
}

// Round 6
// 485.680 us; speedup vs baseline: 1.3676x; 1.0203x over previous
//
#include <hip/hip_runtime.h>

// Problem constants
#define TT   26
#define RR   100000
#define DD   128
#define NN   10
#define BB   16384
#define NUMF 13
#define KP0  3392   // T*D+NUM = 3341 padded to 53*64 (also /32 = 106)

typedef __bf16 bf16x8 __attribute__((ext_vector_type(8)));
typedef float  f32x4  __attribute__((ext_vector_type(4)));
typedef unsigned int u32x2 __attribute__((ext_vector_type(2)));

__device__ __forceinline__ unsigned short f2bf(float f) {
    unsigned int u = __float_as_uint(f);
    u += 0x7FFFu + ((u >> 16) & 1u);          // round-to-nearest-even
    return (unsigned short)(u >> 16);
}

__device__ __forceinline__ void gload_lds16(const void* g, void* l) {
    __builtin_amdgcn_global_load_lds(
        (const __attribute__((address_space(1))) void*)g,
        (__attribute__((address_space(3))) void*)l, 16, 0, 0);
}

// ============ fused: embedding bag (table-major) + numerical fill + weight transposes ===
// Blocks [0,1008): transpose tiles (hide under the fabric-bound embed).
// Blocks [1008, ...): one wave per bag, t-major so the active 51MB table is LLC-resident;
// two rows per gather instruction (lanes 0-31 even row, 32-63 odd, 16B/lane), one
// shfl_xor(32) combine. Trailing waves fill numerical cols [3328,3392).
#define NB_TR 1008

__global__ __launch_bounds__(256) void embed_fused(
    const float* __restrict__ tables, const int* __restrict__ cat,
    const float* __restrict__ numerical, unsigned short* __restrict__ x,
    const float* __restrict__ W0, const float* __restrict__ W1,
    const float* __restrict__ W2,
    unsigned short* __restrict__ w0t, unsigned short* __restrict__ w1t,
    unsigned short* __restrict__ w2t)
{
    __shared__ float tile[64][65];
    int bid = blockIdx.x;
    if (bid < NB_TR) {                         // ---------- transpose path ----------
        const float* in; unsigned short* out; int Kin, KPad, N, tx, ty;
        if (bid < 848)      { in = W0; out = w0t; Kin = TT*DD+NUMF; KPad = KP0;  N = 1024;
                              tx = bid % 53; ty = bid / 53; }
        else if (bid < 976) { in = W1; out = w1t; Kin = 1024; KPad = 1024; N = 512;
                              int rel = bid - 848; tx = rel & 15; ty = rel >> 4; }
        else                { in = W2; out = w2t; Kin = 512;  KPad = 512;  N = 256;
                              int rel = bid - 976; tx = rel & 7;  ty = rel >> 3; }
        int k0 = tx * 64, n0 = ty * 64;
        int c  = threadIdx.x & 63;
        int rr = threadIdx.x >> 6;
        #pragma unroll
        for (int r = rr; r < 64; r += 4) {
            int k = k0 + r, n = n0 + c;
            float v = 0.f;
            if (k < Kin && n < N) v = in[(size_t)k * N + n];
            tile[r][c] = v;
        }
        __syncthreads();
        #pragma unroll
        for (int r = rr; r < 64; r += 4) {
            int n = n0 + r, kp = k0 + c;
            if (n < N && kp < KPad)
                out[(size_t)n * KPad + kp] = f2bf(tile[c][r]);
        }
        return;
    }
    // ---------------------------------- embed path ----------------------------------
    int wid  = (bid - NB_TR) * 4 + (threadIdx.x >> 6);
    int lane = threadIdx.x & 63;
    if (wid >= BB * TT) {                      // numerical fill
        int b = wid - BB * TT;
        unsigned short v = 0;
        if (lane < NUMF) v = f2bf(numerical[b * NUMF + lane]);
        __builtin_nontemporal_store(v, x + (size_t)b * KP0 + TT * DD + lane);
        return;
    }
    int t = wid >> 14;            // wid / BB
    int b = wid & (BB - 1);       // wid % BB
    const int* ip = cat + ((size_t)b * TT + t) * NN;
    const float* tbase = tables + (size_t)t * RR * DD;
    int half = lane >> 5;
    int l5   = lane & 31;
    f32x4 acc = {0.f, 0.f, 0.f, 0.f};
    #pragma unroll
    for (int n2 = 0; n2 < 5; n2++) {
        int r = __builtin_nontemporal_load(ip + 2 * n2 + half);
        f32x4 v = *(const f32x4*)(tbase + (size_t)r * DD + l5 * 4);
        acc += v;
    }
    float t0 = acc[0] + __shfl_xor(acc[0], 32, 64);
    float t1 = acc[1] + __shfl_xor(acc[1], 32, 64);
    float t2 = acc[2] + __shfl_xor(acc[2], 32, 64);
    float t3 = acc[3] + __shfl_xor(acc[3], 32, 64);
    if (half == 0) {
        u32x2 pk;
        pk[0] = (unsigned int)f2bf(t0) | ((unsigned int)f2bf(t1) << 16);
        pk[1] = (unsigned int)f2bf(t2) | ((unsigned int)f2bf(t3) << 16);
        __builtin_nontemporal_store(pk, (u32x2*)(x + (size_t)b * KP0 + t * DD + l5 * 4));
    }
}

// ======================= 256x256 4-phase counted-vmcnt MFMA GEMM =======================
// BM=BN=256, rotation unit = half-K tile (BK=32) over 4 LDS buffers (4x32KB=128KB).
// Computing half-tile h reads buf h%4 while staging h+2 into buf (h+2)%4 -> disjoint,
// so counted vmcnt(4) at the boundary is race-free by construction.
// LDS layout per buffer: A then B, row-pair interleaved:
// byte = (r>>1)*128 + (r&1)*64 + k16*16 -> column reads 2-way bank aliased (free).
#define G_BUFB 32768

__global__ __launch_bounds__(512, 2) void gemm256(
    const unsigned short* __restrict__ A,    // [M][K] bf16
    const unsigned short* __restrict__ Bt,   // [N][K] bf16
    const float* __restrict__ bias,
    unsigned short* __restrict__ C,          // [M][N] bf16
    int M, int N, int K, int do_relu)
{
    extern __shared__ __align__(16) char lds[];
    const int tid  = threadIdx.x;
    const int lane = tid & 63;
    const int w    = tid >> 6;
    const int wm   = w >> 2, wn = w & 3;      // 2 x 4 waves, wave-tile 128x64

    // XCD-aware bijective swizzle (nwg % 8 == 0); same-by tiles stay on one XCD
    int nwg  = gridDim.x * gridDim.y;
    int orig = blockIdx.y * gridDim.x + blockIdx.x;
    int cpx  = nwg >> 3;
    int swz  = (orig & 7) * cpx + (orig >> 3);
    int bx   = swz % gridDim.x;
    int by   = swz / gridDim.x;
    const int m0 = by * 256, n0 = bx * 256;

    const int NT = K >> 5;                    // number of half-K (32) tiles

    f32x4 acc[8][4];
    #pragma unroll
    for (int i = 0; i < 8; i++)
        #pragma unroll
        for (int j = 0; j < 4; j++) {
            f32x4 z = {0.f, 0.f, 0.f, 0.f};
            acc[i][j] = z;
        }

    auto stage_unit = [&](int h, int u) {
        int i    = ((u & 1) << 9) + tid;
        int row  = 2 * (i >> 3) + ((i >> 2) & 1);
        int col8 = i & 3;
        const unsigned short* base = (u < 2)
            ? (A  + (size_t)(m0 + row) * K)
            : (Bt + (size_t)(n0 + row) * K);
        const unsigned short* g = base + (h << 5) + col8 * 8;
        char* l = lds + (size_t)(h & 3) * G_BUFB + ((u >> 1) << 14) + ((u & 1) << 13)
                      + ((tid >> 6) << 10);
        gload_lds16(g, l);
    };

    #pragma unroll
    for (int u = 0; u < 4; u++) stage_unit(0, u);
    #pragma unroll
    for (int u = 0; u < 4; u++) stage_unit(1, u);
    asm volatile("s_waitcnt vmcnt(4)" ::: "memory");
    __builtin_amdgcn_s_barrier();

    for (int h = 0; h < NT; ++h) {
        const char* bufR = lds + (size_t)(h & 3) * G_BUFB;
        const bool  do_stage = (h + 2) < NT;

        bf16x8 bfr[4];
        #pragma unroll
        for (int p = 0; p < 4; p++) {          // phase p computes m-frags 2p, 2p+1
            if (do_stage) stage_unit(h + 2, p);
            if (p == 0) {
                #pragma unroll
                for (int nf = 0; nf < 4; nf++) {
                    int r = wn * 64 + nf * 16 + (lane & 15);
                    bfr[nf] = *(const bf16x8*)(bufR + 16384 + ((r >> 1) << 7)
                                               + ((r & 1) << 6) + ((lane >> 4) << 4));
                }
            }
            bf16x8 afr[2];
            #pragma unroll
            for (int q = 0; q < 2; q++) {
                int r = wm * 128 + (2 * p + q) * 16 + (lane & 15);
                afr[q] = *(const bf16x8*)(bufR + ((r >> 1) << 7)
                                          + ((r & 1) << 6) + ((lane >> 4) << 4));
            }
            asm volatile("s_waitcnt lgkmcnt(0)" ::: "memory");
            __builtin_amdgcn_sched_barrier(0);
            __builtin_amdgcn_s_setprio(1);
            #pragma unroll
            for (int q = 0; q < 2; q++)
                #pragma unroll
                for (int nf = 0; nf < 4; nf++)
                    acc[2 * p + q][nf] = __builtin_amdgcn_mfma_f32_16x16x32_bf16(
                        afr[q], bfr[nf], acc[2 * p + q][nf], 0, 0, 0);
            __builtin_amdgcn_s_setprio(0);
            if (p < 3) __builtin_amdgcn_s_barrier();
        }
        if (do_stage) asm volatile("s_waitcnt vmcnt(4)" ::: "memory");
        else          asm volatile("s_waitcnt vmcnt(0)" ::: "memory");
        __builtin_amdgcn_s_barrier();
    }

    // epilogue: bias + relu + bf16 store.  C/D map: col=lane&15, row=4*(lane>>4)+j
    #pragma unroll
    for (int mf = 0; mf < 8; mf++) {
        int row_base = m0 + wm * 128 + mf * 16 + (lane >> 4) * 4;
        #pragma unroll
        for (int nf = 0; nf < 4; nf++) {
            int col = n0 + wn * 64 + nf * 16 + (lane & 15);
            float bv = bias[col];
            #pragma unroll
            for (int j = 0; j < 4; j++) {
                float v = acc[mf][nf][j] + bv;
                if (do_relu) v = v > 0.f ? v : 0.f;
                C[(size_t)(row_base + j) * N + col] = f2bf(v);
            }
        }
    }
}

// ============= fused last stage: out = relu(h2 @ W2 + b2) . W3 + b3 ====================
// 64-row x 256-col tiles (grid 256 = full CU coverage), 4 waves, wave-tile 32x128.
// h3 never materialized: epilogue does relu+dot in-register, shfl_xor reduce over the
// 16 col-lanes, tiny LDS cross-wave (wn) add.
__global__ __launch_bounds__(256) void gemm_last(
    const unsigned short* __restrict__ A,    // h2 [BB][512] bf16
    const unsigned short* __restrict__ Bt,   // w2t [256][512] bf16
    const float* __restrict__ bias,          // b2 [256]
    const float* __restrict__ W3,            // [256]
    const float* __restrict__ b3,            // [1]
    float* __restrict__ out)                 // [BB]
{
    __shared__ __align__(16) unsigned short As[64 * 64];
    __shared__ __align__(16) unsigned short Bs[256 * 64];
    __shared__ float red[2][64];
    const int tid  = threadIdx.x;
    const int lane = tid & 63;
    const int w    = tid >> 6;
    const int wm   = w >> 1, wn = w & 1;      // wave-tile 32 rows x 128 cols
    const int m0   = blockIdx.x * 64;
    const int K = 512;

    f32x4 acc[2][8];
    #pragma unroll
    for (int i = 0; i < 2; i++)
        #pragma unroll
        for (int j = 0; j < 8; j++) {
            f32x4 z = {0.f, 0.f, 0.f, 0.f};
            acc[i][j] = z;
        }

    for (int k0 = 0; k0 < K; k0 += 64) {
        #pragma unroll
        for (int j = 0; j < 2; j++) {          // A: 64 rows x 64k = 512 chunks
            int ch = j * 256 + tid;
            const unsigned short* g = A + (size_t)(m0 + (ch >> 3)) * K + k0 + (ch & 7) * 8;
            gload_lds16(g, As + (size_t)(j * 256 + (tid & 192)) * 8);
        }
        #pragma unroll
        for (int j = 0; j < 8; j++) {          // B: 256 rows x 64k = 2048 chunks
            int ch = j * 256 + tid;
            const unsigned short* g = Bt + (size_t)(ch >> 3) * K + k0 + (ch & 7) * 8;
            gload_lds16(g, Bs + (size_t)(j * 256 + (tid & 192)) * 8);
        }
        __syncthreads();
        #pragma unroll
        for (int kk = 0; kk < 2; kk++) {
            bf16x8 af[2], bfv[8];
            #pragma unroll
            for (int mi = 0; mi < 2; mi++) {
                int off = (wm * 32 + mi * 16 + (lane & 15)) * 64 + kk * 32 + (lane >> 4) * 8;
                af[mi] = *(const bf16x8*)(As + off);
            }
            #pragma unroll
            for (int ni = 0; ni < 8; ni++) {
                int off = (wn * 128 + ni * 16 + (lane & 15)) * 64 + kk * 32 + (lane >> 4) * 8;
                bfv[ni] = *(const bf16x8*)(Bs + off);
            }
            #pragma unroll
            for (int mi = 0; mi < 2; mi++)
                #pragma unroll
                for (int ni = 0; ni < 8; ni++)
                    acc[mi][ni] = __builtin_amdgcn_mfma_f32_16x16x32_bf16(
                        af[mi], bfv[ni], acc[mi][ni], 0, 0, 0);
        }
        __syncthreads();
    }

    // epilogue: per-thread partial dot over its 8 cols, then reduce
    float psum[2][4] = {{0.f,0.f,0.f,0.f},{0.f,0.f,0.f,0.f}};
    #pragma unroll
    for (int mi = 0; mi < 2; mi++)
        #pragma unroll
        for (int ni = 0; ni < 8; ni++) {
            int col = wn * 128 + ni * 16 + (lane & 15);
            float wv = W3[col], bv = bias[col];
            #pragma unroll
            for (int j = 0; j < 4; j++) {
                float v = acc[mi][ni][j] + bv;
                v = v > 0.f ? v : 0.f;
                psum[mi][j] += v * wv;
            }
        }
    #pragma unroll
    for (int off = 1; off < 16; off <<= 1)
        #pragma unroll
        for (int mi = 0; mi < 2; mi++)
            #pragma unroll
            for (int j = 0; j < 4; j++)
                psum[mi][j] += __shfl_xor(psum[mi][j], off, 64);
    if ((lane & 15) == 0) {
        #pragma unroll
        for (int mi = 0; mi < 2; mi++)
            #pragma unroll
            for (int j = 0; j < 4; j++)
                red[wn][wm * 32 + mi * 16 + (lane >> 4) * 4 + j] = psum[mi][j];
    }
    __syncthreads();
    if (tid < 64) out[m0 + tid] = red[0][tid] + red[1][tid] + b3[0];
}

extern "C" void kernel_launch(void* const* d_in, const int* in_sizes, int n_in,
                              void* d_out, int out_size, void* d_ws, size_t ws_size,
                              hipStream_t stream)
{
    const float* numerical = (const float*)d_in[0];
    const int*   cat       = (const int*)d_in[1];
    const float* tables    = (const float*)d_in[2];
    const float* W0 = (const float*)d_in[3];
    const float* b0 = (const float*)d_in[4];
    const float* W1 = (const float*)d_in[5];
    const float* b1 = (const float*)d_in[6];
    const float* W2 = (const float*)d_in[7];
    const float* b2 = (const float*)d_in[8];
    const float* W3 = (const float*)d_in[9];
    const float* b3 = (const float*)d_in[10];
    float* out = (float*)d_out;

    // workspace layout (bf16 elements); h2 aliases x (dead after L0)
    unsigned short* x   = (unsigned short*)d_ws;            // [16384][3392]
    unsigned short* w0t = x   + (size_t)BB * KP0;           // [1024][3392]
    unsigned short* w1t = w0t + (size_t)1024 * KP0;         // [512][1024]
    unsigned short* w2t = w1t + (size_t)512 * 1024;         // [256][512]
    unsigned short* h1  = w2t + (size_t)256 * 512;          // [16384][1024]
    unsigned short* h2  = x;                                // [16384][512]

    (void)hipFuncSetAttribute((const void*)gemm256,
                              hipFuncAttributeMaxDynamicSharedMemorySize, 131072);

    embed_fused<<<dim3(NB_TR + (BB * TT + BB) / 4), 256, 0, stream>>>(
        tables, cat, numerical, x, W0, W1, W2, w0t, w1t, w2t);

    gemm256<<<dim3(1024 / 256, BB / 256), 512, 131072, stream>>>(
        x, w0t, b0, h1, BB, 1024, KP0, 1);
    gemm256<<<dim3(512 / 256, BB / 256), 512, 131072, stream>>>(
        h1, w1t, b1, h2, BB, 512, 1024, 1);
    gemm_last<<<dim3(BB / 64), 256, 0, stream>>>(h2, w2t, b2, W3, b3, out);
}